// Round 9
// baseline (37198.529 us; speedup 1.0000x reference)
//
#include <hip/hip_runtime.h>
#include <math.h>

#define B 128
#define H 256
#define V 130
#define L 100
#define G3 768
#define BH (B*H)
#define NWG 256
#define NT 1024

// ---- workspace layout (4-byte words) ----
#define OFF_FLAGS 0               // 32 group counters x 16-int pad
#define OFF_XRANK 512             // 8 per-XCD rank counters x 16-int pad
#define OFF_HID   1024
#define OFF_Z1    (OFF_HID + BH)
#define OFF_Z2    (OFF_Z1 + 3*B*G3)
#define OFF_G1HA  (OFF_Z2 + 3*B*G3)
#define OFF_G1HB  (OFF_G1HA + 3*BH)
#define OFF_H2A   (OFF_G1HB + 3*BH)
#define OFF_H2B   (OFF_H2A + 3*BH)
#define OFF_CTXA  (OFF_H2B + 3*BH)
#define OFF_CTXB  (OFF_CTXA + BH)
#define OFF_U0    (OFF_CTXB + BH)
#define OFF_U1    (OFF_U0 + 3*BH)
#define OFF_NOTE  (OFF_U1 + 3*BH)

typedef float v4f __attribute__((ext_vector_type(4)));

__device__ __forceinline__ float sigmoidf_(float x) { return 1.0f / (1.0f + expf(-x)); }

// ---- XCD-L2-coherent accessors (sc0 ONLY): stores write through to the
// ---- owning XCD's L2; loads bypass L1 and hit the same L2 (~300cy, cached).
// ---- Valid because each comm group lives entirely on ONE XCD (see claim).
__device__ __forceinline__ v4f load_coh4(const float* p) {
  v4f v;
  asm volatile("global_load_dwordx4 %0, %1, off sc0" : "=v"(v) : "v"(p) : "memory");
  return v;  // caller must s_waitcnt vmcnt before use
}
__device__ __forceinline__ void store_coh(float* p, float v) {
  asm volatile("global_store_dword %0, %1, off sc0" :: "v"(p), "v"(v) : "memory");
}
__device__ __forceinline__ void store_coh4(float* p, v4f v) {
  asm volatile("global_store_dwordx4 %0, %1, off sc0" :: "v"(p), "v"(v) : "memory");
}
__device__ __forceinline__ void waitvm0() {
  asm volatile("s_waitcnt vmcnt(0)" ::: "memory");
}

// ---------------------------------------------------------------------------
// Group barrier: 8 co-XCD WGs, single LLC counter, thread-0 spin.
// Data visibility: sc0 stores drained to XCD-L2 (vmcnt0) before arrival;
// readers are on the same XCD -> L2 is the common coherence point.
// ---------------------------------------------------------------------------
__device__ __forceinline__ void group_barrier(int* cnt, int grp, int target, int tid) {
  waitvm0();
  __syncthreads();
  if (tid == 0) {
    int* c = cnt + grp * 16;
    __hip_atomic_fetch_add(c, 1, __ATOMIC_RELAXED, __HIP_MEMORY_SCOPE_AGENT);
    while (__hip_atomic_load(c, __ATOMIC_RELAXED, __HIP_MEMORY_SCOPE_AGENT) < target)
      __builtin_amdgcn_s_sleep(1);
  }
  __syncthreads();
}

// ---------------------------------------------------------------------------
// One GRU phase. WG tile: 4 rows x 32 cols. Thread: kq=tid&7 (K eighth),
// row=(tid>>3)&3, col=tid>>5. x staged to LDS via sc0 loads (XCD L2);
// weights via normal cached loads (phase working set ~2-3MB, L2-resident).
// ---------------------------------------------------------------------------
template <int NCHUNK>
__device__ void gru_phase(
    const float* __restrict__ xc0, const float* __restrict__ xc1,
    const float* __restrict__ xc2, const float* __restrict__ xc3,
    const float* __restrict__ wih, int wih_stride,
    const float* __restrict__ whh,
    const float* __restrict__ zadd,   // [B][768] precomputed z@W_z.T + bih, or null
    const float* __restrict__ bih,    // used when zadd == null
    const float* __restrict__ bhh,
    float* __restrict__ out0, float* __restrict__ out1,
    float* smem, int row0, int col0, int tid)
{
  const float* xc[4] = {xc0, xc1, xc2, xc3};
  // ---- stage x: NCHUNK chunks x 4 rows x 256 floats; 1 float4/thread ----
  v4f stg;
  int sc = 0, srr = 0, sk4 = 0;
  const int nldv = NCHUNK * 256;
  if (tid < nldv) {
    sc  = tid >> 8;
    const int r = tid & 255;
    srr = r >> 6;
    sk4 = (r & 63) << 2;
    stg = load_coh4(xc[sc] + (size_t)(row0 + srr) * H + sk4);
  }
  __syncthreads();   // previous phase done with LDS
  waitvm0();
  if (tid < nldv) {
    const int sw = (sk4 >> 6) * 65 + (sk4 & 63);   // sub-row swizzle
    *reinterpret_cast<v4f*>(smem + sc * 1040 + srr * 260 + sw) = stg;
  }
  __syncthreads();

  const int kq    = tid & 7;
  const int row_l = (tid >> 3) & 3;
  const int col_l = tid >> 5;          // 0..31
  const int col   = col0 + col_l;

  const int klen   = NCHUNK * 32;      // K/8 per thread
  const int kstart = kq * klen;
  const int c      = kstart >> 8;      // chunk (never crossed: klen <= 128)
  const int koff   = kstart & 255;
  const bool is_ih = (c < NCHUNK - 1);

  const float* wb;
  int wstr;
  if (is_ih) { wstr = wih_stride; wb = wih + (size_t)col * wstr + (c * 256 + koff); }
  else       { wstr = 256;        wb = whh + (size_t)col * 256 + koff; }
  const float* wR = wb;
  const float* wZ = wb + (size_t)256 * wstr;
  const float* wN = wb + (size_t)512 * wstr;
  const float* xrow = smem + c * 1040 + row_l * 260;

  float aR = 0.f, aZ = 0.f, aN = 0.f;
#pragma unroll
  for (int kb = 0; kb < (klen == 64 ? 1 : 2); ++kb) {
    const int kof2 = koff + kb * 64;
    const float* xb = xrow + (kof2 >> 6) * 65;
    const float* wRb = wR + kb * 64;
    const float* wZb = wZ + kb * 64;
    const float* wNb = wN + kb * 64;
#pragma unroll
    for (int k = 0; k < 64; k += 4) {
      v4f xv = *reinterpret_cast<const v4f*>(xb + k);
      v4f vR = *reinterpret_cast<const v4f*>(wRb + k);
      v4f vZ = *reinterpret_cast<const v4f*>(wZb + k);
      v4f vN = *reinterpret_cast<const v4f*>(wNb + k);
      aR += xv.x * vR.x; aR += xv.y * vR.y; aR += xv.z * vR.z; aR += xv.w * vR.w;
      aZ += xv.x * vZ.x; aZ += xv.y * vZ.y; aZ += xv.z * vZ.z; aZ += xv.w * vZ.w;
      aN += xv.x * vN.x; aN += xv.y * vN.y; aN += xv.z * vN.z; aN += xv.w * vN.w;
    }
  }
  float aNi = is_ih ? aN : 0.f;
  float aNh = is_ih ? 0.f : aN;
#pragma unroll
  for (int m = 1; m <= 4; m <<= 1) {
    aR  += __shfl_xor(aR, m);
    aZ  += __shfl_xor(aZ, m);
    aNi += __shfl_xor(aNi, m);
    aNh += __shfl_xor(aNh, m);
  }
  if (kq == 0) {
    float bR, bZ, bN;
    if (zadd) {
      const float* zp = zadd + (size_t)(row0 + row_l) * G3;
      bR = zp[col]; bZ = zp[256 + col]; bN = zp[512 + col];
    } else {
      bR = bih[col]; bZ = bih[256 + col]; bN = bih[512 + col];
    }
    const float hR = bhh[col], hZ = bhh[256 + col], hN = bhh[512 + col];
    const float hold = smem[(NCHUNK - 1) * 1040 + row_l * 260 + (col >> 6) * 65 + (col & 63)];
    const float rg = sigmoidf_(aR + bR + hR);
    const float ug = sigmoidf_(aZ + bZ + hZ);
    const float ng = tanhf(aNi + bN + rg * (aNh + hN));
    const float hnew = (1.f - ug) * ng + ug * hold;
    const size_t o = (size_t)(row0 + row_l) * H + col;
    store_coh(out0 + o, hnew);
    if (out1) store_coh(out1 + o, hnew);
  }
}

// ---------------------------------------------------------------------------
// Out phase: logits=(u+h2)@ow.T+ob, store d_out slice, argmax (first-index
// ties), note[row]=emb[argmax]. One WG per row (slices 0..3 active).
// ---------------------------------------------------------------------------
__device__ void out_phase(
    const float* __restrict__ u0i, const float* __restrict__ h2i,
    const float* __restrict__ ow, const float* __restrict__ ob,
    const float* __restrict__ embi,
    float* __restrict__ note_i, float* __restrict__ outp,
    float* smem, int* sidx, int row, bool active, int tid)
{
  if (!active) return;
  v4f a4, b4;
  if (tid < 64) {
    a4 = load_coh4(u0i + (size_t)row * H + tid * 4);
    b4 = load_coh4(h2i + (size_t)row * H + tid * 4);
  }
  __syncthreads();
  if (tid < 64) {
    waitvm0();
    *reinterpret_cast<v4f*>(smem + tid * 4) = a4 + b4;
  }
  __syncthreads();

  const int v = tid >> 2, kq = tid & 3;
  if (v < V) {
    const float* wrow = ow + (size_t)v * H + kq * 64;
    const float* xr = smem + kq * 64;
    float acc = 0.f;
#pragma unroll
    for (int k = 0; k < 64; k += 4) {
      v4f xv = *reinterpret_cast<const v4f*>(xr + k);
      v4f wv = *reinterpret_cast<const v4f*>(wrow + k);
      acc += xv.x * wv.x; acc += xv.y * wv.y; acc += xv.z * wv.z; acc += xv.w * wv.w;
    }
    acc += __shfl_xor(acc, 1);
    acc += __shfl_xor(acc, 2);
    if (kq == 0) {
      acc += ob[v];
      store_coh(outp + v, acc);   // d_out slice
      smem[256 + v] = acc;        // vals area
    }
  }
  __syncthreads();
  if (tid < 64) {
    float* vals = smem + 256;
    float bv = vals[tid]; int bi = tid;
    float c1 = vals[64 + tid];
    if (c1 > bv) { bv = c1; bi = 64 + tid; }
    if (tid < 2) { float c2 = vals[128 + tid]; if (c2 > bv) { bv = c2; bi = 128 + tid; } }
#pragma unroll
    for (int off = 32; off; off >>= 1) {
      float ov = __shfl_down(bv, off);
      int oi = __shfl_down(bi, off);
      if (ov > bv || (ov == bv && oi < bi)) { bv = ov; bi = oi; }
    }
    if (tid == 0) *sidx = bi;
  }
  __syncthreads();
  const int idx = *sidx;
  if (tid < 64) {
    v4f e = *reinterpret_cast<const v4f*>(embi + (size_t)idx * H + tid * 4);
    store_coh4(note_i + (size_t)row * H + tid * 4, e);
  }
}

// ---------------------------------------------------------------------------
// Persistent decode: 256 WGs x 1024 threads. 32 groups of 4 rows; each group
// = 8 WGs ON ONE XCD (slice = 32-col range). Guarantee: LDS>80KB forces
// 1 WG/CU and grid==CU count, so every XCD hosts exactly 32 WGs ->
// per-XCD rank is always 0..31. Activation exchange stays in the XCD's L2
// (sc0-only accesses); barrier counters via LLC atomics.
// ---------------------------------------------------------------------------
__global__ __launch_bounds__(NT) void decoder_persistent(
    const float* __restrict__ g1wih, const float* __restrict__ g1whh,
    const float* __restrict__ g1bhh,
    const float* __restrict__ g2wih, const float* __restrict__ g2whh,
    const float* __restrict__ g2bhh,
    const float* __restrict__ cwih, const float* __restrict__ cwhh,
    const float* __restrict__ cbih, const float* __restrict__ cbhh,
    const float* __restrict__ outw, const float* __restrict__ outb,
    const float* __restrict__ emb,
    float* __restrict__ out, float* __restrict__ wsf)
{
  __shared__ float smem[20608];   // 82,432 B > 80 KiB -> 1 WG/CU
  __shared__ int sidx;
  __shared__ int s_tile;
  int* cnt   = reinterpret_cast<int*>(wsf) + OFF_FLAGS;
  int* xrank = reinterpret_cast<int*>(wsf) + OFF_XRANK;
  float* Z1   = wsf + OFF_Z1;
  float* Z2   = wsf + OFF_Z2;
  float* g1h[2] = {wsf + OFF_G1HA, wsf + OFF_G1HB};
  float* h2b[2] = {wsf + OFF_H2A,  wsf + OFF_H2B};
  float* ctx[2] = {wsf + OFF_CTXA, wsf + OFF_CTXB};
  float* U0   = wsf + OFF_U0;
  float* U1   = wsf + OFF_U1;
  float* note = wsf + OFF_NOTE;

  const int tid = threadIdx.x;

  // ---- XCD-local tile claim: rank within physical XCD (always 0..31) ----
  if (tid == 0) {
    int xcc;
    asm("s_getreg_b32 %0, hwreg(20, 0, 32)" : "=s"(xcc));  // HW_REG_XCC_ID
    xcc &= 7;
    int rk = __hip_atomic_fetch_add(xrank + xcc * 16, 1,
                                    __ATOMIC_RELAXED, __HIP_MEMORY_SCOPE_AGENT) & 31;
    s_tile = xcc * 32 + rk;
  }
  __syncthreads();
  const int tile  = s_tile;
  const int xcc   = tile >> 5;
  const int rank  = tile & 31;
  const int g     = xcc * 4 + (rank >> 3);   // global group 0..31 (XCD-local!)
  const int slice = rank & 7;                // col slice within group
  const int col0 = slice * 32;
  const int row0 = g * 4;
  const bool oact = (slice < 4);
  const int orow = row0 + slice;
  int ep = 0;

  for (int t = 0; t < L; ++t) {
    const int rbk = t & 1, wbk = (t + 1) & 1;
    for (int s = 0; s < 3; ++s) {
      gru_phase<2>(note + (size_t)s * BH, g1h[rbk] + (size_t)s * BH, nullptr, nullptr,
                   g1wih + (size_t)s * G3 * 512, 512, g1whh + (size_t)s * G3 * H,
                   Z1 + (size_t)s * B * G3, nullptr, g1bhh + (size_t)s * G3,
                   g1h[wbk] + (size_t)s * BH, U0 + (size_t)s * BH,
                   smem, row0, col0, tid);
    }
    group_barrier(cnt, g, (++ep) * 8, tid);
    for (int i = 0; i < 3; ++i) {
      const int j = 3 * t + i;
      const float* us0 = (0 < i ? U1 : U0) + 0 * BH;
      const float* us1 = (1 < i ? U1 : U0) + 1 * BH;
      const float* us2 = (2 < i ? U1 : U0) + 2 * BH;
      gru_phase<4>(us0, us1, us2, ctx[j & 1],
                   cwih, G3, cwhh,
                   nullptr, cbih, cbhh,
                   ctx[(j + 1) & 1], nullptr,
                   smem, row0, col0, tid);
      group_barrier(cnt, g, (++ep) * 8, tid);
      gru_phase<2>(ctx[(j + 1) & 1], h2b[rbk] + (size_t)i * BH, nullptr, nullptr,
                   g2wih + (size_t)i * G3 * 512, 512, g2whh + (size_t)i * G3 * H,
                   Z2 + (size_t)i * B * G3, nullptr, g2bhh + (size_t)i * G3,
                   h2b[wbk] + (size_t)i * BH, nullptr,
                   smem, row0, col0, tid);
      group_barrier(cnt, g, (++ep) * 8, tid);
      out_phase(U0 + (size_t)i * BH, h2b[wbk] + (size_t)i * BH,
                outw + (size_t)i * V * H, outb + (size_t)i * V, emb + (size_t)i * V * H,
                note + (size_t)i * BH,
                out + (size_t)i * B * L * V + (size_t)orow * L * V + (size_t)t * V,
                smem, &sidx, orow, oact, tid);
      group_barrier(cnt, g, (++ep) * 8, tid);
      gru_phase<2>(note + (size_t)i * BH, U0 + (size_t)i * BH, nullptr, nullptr,
                   g1wih + (size_t)1 * G3 * 512, 512, g1whh + (size_t)1 * G3 * H,
                   Z1 + (size_t)1 * B * G3, nullptr, g1bhh + (size_t)1 * G3,
                   U1 + (size_t)i * BH, nullptr,
                   smem, row0, col0, tid);
      group_barrier(cnt, g, (++ep) * 8, tid);
    }
  }
}

// ---------------------------------------------------------------------------
// Prologue kernels (outside the decode loop; cheap)
// ---------------------------------------------------------------------------
__global__ __launch_bounds__(256) void hid_kernel(
    const float* __restrict__ z, const float* __restrict__ hw,
    const float* __restrict__ hb, float* __restrict__ hidden)
{
  __shared__ float xs[32][260];
  const int tid = threadIdx.x;
  const int r = tid & 31, hc = tid >> 5;
  const int row0 = blockIdx.y * 32;
  const int col = blockIdx.x * 8 + hc;
  for (int jj = tid; jj < 32 * 64; jj += 256) {
    const int rr = jj >> 6, k4 = (jj & 63) << 2;
    *reinterpret_cast<float4*>(&xs[rr][k4]) =
        *reinterpret_cast<const float4*>(z + (size_t)(row0 + rr) * H + k4);
  }
  __syncthreads();
  float acc = 0.f;
  const float* wrow = hw + (size_t)col * H;
#pragma unroll 8
  for (int k = 0; k < 256; k += 4) {
    const float4 xv = *reinterpret_cast<const float4*>(&xs[r][k]);
    const float4 wv = *reinterpret_cast<const float4*>(wrow + k);
    acc += xv.x * wv.x; acc += xv.y * wv.y; acc += xv.z * wv.z; acc += xv.w * wv.w;
  }
  hidden[(size_t)(row0 + r) * H + col] = tanhf(acc + hb[col]);
}

__global__ __launch_bounds__(256) void zpre_kernel(
    const float* __restrict__ z, const float* __restrict__ wih,
    const float* __restrict__ bih, float* __restrict__ zout)
{
  __shared__ float xs[32][260];
  const int tid = threadIdx.x;
  const int r = tid & 31, hc = tid >> 5;
  const int row0 = blockIdx.y * 32;
  const int gr = blockIdx.x * 8 + hc;   // 0..2303
  const int s = gr / G3;
  const int gg = gr - s * G3;
  for (int jj = tid; jj < 32 * 64; jj += 256) {
    const int rr = jj >> 6, k4 = (jj & 63) << 2;
    *reinterpret_cast<float4*>(&xs[rr][k4]) =
        *reinterpret_cast<const float4*>(z + (size_t)(row0 + rr) * H + k4);
  }
  __syncthreads();
  float acc = 0.f;
  const float* wrow = wih + (size_t)gr * 512 + 256;
#pragma unroll 8
  for (int k = 0; k < 256; k += 4) {
    const float4 xv = *reinterpret_cast<const float4*>(&xs[r][k]);
    const float4 wv = *reinterpret_cast<const float4*>(wrow + k);
    acc += xv.x * wv.x; acc += xv.y * wv.y; acc += xv.z * wv.z; acc += xv.w * wv.w;
  }
  zout[((size_t)(s * B + row0 + r)) * G3 + gg] = acc + bih[gr];
}

__global__ __launch_bounds__(256) void init_copy(
    const float* __restrict__ hidden, float* __restrict__ g1h0,
    float* __restrict__ h20, float* __restrict__ ctx0)
{
  const int e = blockIdx.x * 256 + threadIdx.x;
  const float v = hidden[e];
  ctx0[e] = v;
  for (int s = 0; s < 3; ++s) {
    g1h0[(size_t)s * BH + e] = v;
    h20[(size_t)s * BH + e] = v;
  }
}

__global__ __launch_bounds__(256) void init_note(
    const float* __restrict__ emb, float* __restrict__ note)
{
  const int e = blockIdx.x * 256 + threadIdx.x;   // 0..3*B*H
  const int s = e / BH;
  const int c = e & (H - 1);
  note[e] = emb[(size_t)s * V * H + c];
}

__global__ void zero_flags(int* flags) { flags[threadIdx.x] = 0; }

extern "C" void kernel_launch(void* const* d_in, const int* in_sizes, int n_in,
                              void* d_out, int out_size, void* d_ws, size_t ws_size,
                              hipStream_t stream) {
  const float* z     = (const float*)d_in[0];
  const float* g1wih = (const float*)d_in[1];
  const float* g1whh = (const float*)d_in[2];
  const float* g1bih = (const float*)d_in[3];
  const float* g1bhh = (const float*)d_in[4];
  const float* g2wih = (const float*)d_in[5];
  const float* g2whh = (const float*)d_in[6];
  const float* g2bih = (const float*)d_in[7];
  const float* g2bhh = (const float*)d_in[8];
  const float* cwih  = (const float*)d_in[9];
  const float* cwhh  = (const float*)d_in[10];
  const float* cbih  = (const float*)d_in[11];
  const float* cbhh  = (const float*)d_in[12];
  const float* outw  = (const float*)d_in[13];
  const float* outb  = (const float*)d_in[14];
  const float* hidw  = (const float*)d_in[15];
  const float* hidb  = (const float*)d_in[16];
  const float* emb   = (const float*)d_in[17];
  float* out = (float*)d_out;
  float* wsf = (float*)d_ws;
  int* flags = (int*)d_ws;

  const dim3 blk(256);
  hid_kernel<<<dim3(32, 4), blk, 0, stream>>>(z, hidw, hidb, wsf + OFF_HID);
  zpre_kernel<<<dim3(288, 4), blk, 0, stream>>>(z, g1wih, g1bih, wsf + OFF_Z1);
  zpre_kernel<<<dim3(288, 4), blk, 0, stream>>>(z, g2wih, g2bih, wsf + OFF_Z2);
  init_copy<<<128, blk, 0, stream>>>(wsf + OFF_HID, wsf + OFF_G1HA,
                                     wsf + OFF_H2A, wsf + OFF_CTXA);
  init_note<<<384, blk, 0, stream>>>(emb, wsf + OFF_NOTE);
  zero_flags<<<1, 1024, 0, stream>>>(flags);

  decoder_persistent<<<NWG, NT, 0, stream>>>(
      g1wih, g1whh, g1bhh, g2wih, g2whh, g2bhh,
      cwih, cwhh, cbih, cbhh, outw, outb, emb, out, wsf);
}